// Round 9
// baseline (56.818 us; speedup 1.0000x reference)
//
#include <hip/hip_runtime.h>

#define LSEQ 512
#define NCH  321
#define BATCH 128
#define KAVG 25
#define PAD  12
#define NB1A 8
#define ROWS1A 64      // LSEQ / NB1A

#define BANDS 8
#define BROWS 64       // rows per band (LSEQ / BANDS)
#define ITERS_V 16     // BROWS / 4 (four rows per f32x4 iteration)
#define RTHREADS 384   // 6 waves; NCH = 321 active lanes

#define ROWS_W 32
#define WBLOCKS (LSEQ / ROWS_W)   // 16
#define CHUNKW  (ROWS_W * NCH)    // 10272 dwords, /4 = 2568 float4

typedef float f32x4 __attribute__((ext_vector_type(4)));

// Exact XTX for t = -512..-1:  [[L, S1],[S1, S2]]
constexpr double S1d  = -131328.0;
constexpr double S2d  = 44870400.0;
constexpr double DETD = 512.0 * S2d - S1d * S1d;
constexpr double I00  = S2d / DETD;
constexpr double I01  = -S1d / DETD;
constexpr double I11  = 512.0 / DETD;

// Stage 1: partial column sums of W (row-major [p][l]), 64 rows per block.
__global__ __launch_bounds__(512) void colsum_kernel(const float* __restrict__ W,
                                                     float* __restrict__ part0,
                                                     float* __restrict__ part1) {
    int l = threadIdx.x;
    int p0 = blockIdx.x * ROWS1A;
    double s0 = 0.0, s1 = 0.0;
#pragma unroll
    for (int r = 0; r < ROWS1A; ++r) {
        float w = W[(p0 + r) * LSEQ + l];
        s0 += (double)w;
        s1 += (double)(p0 + r - LSEQ) * (double)w;
    }
    part0[blockIdx.x * LSEQ + l] = (float)s0;
    part1[blockIdx.x * LSEQ + l] = (float)s1;
}

// Stage 2 (reduce, streaming, vectorized): block = (band, b). Inline prep
// prologue builds alpha/beta (+ bias consts) in LDS, then the block streams
// 64 contiguous rows of x as f32x4 (4 rows = 1284 floats = 321 f32x4 per
// iteration; thread t owns fixed channels n_j = (4t+j) mod 321).
__global__ __launch_bounds__(RTHREADS) void reduce_kernel(const float* __restrict__ x,
                                                          const float* __restrict__ part0,
                                                          const float* __restrict__ part1,
                                                          const float* __restrict__ bvec,
                                                          float* __restrict__ P0,
                                                          float* __restrict__ P1) {
    __shared__ double w0d[LSEQ], w1d[LSEQ];
    __shared__ double r0[LSEQ], r1[LSEQ];
    __shared__ float la[LSEQ], lbb[LSEQ];
    __shared__ float cbuf0[NCH], cbuf1[NCH];
    __shared__ float cc0, cc1;

    int tid = threadIdx.x;

    // ---- inline prep (strided over l) ----
    for (int l = tid; l < LSEQ; l += RTHREADS) {
        double s0 = 0.0, s1 = 0.0;
#pragma unroll
        for (int j = 0; j < NB1A; ++j) {
            s0 += (double)part0[j * LSEQ + l];
            s1 += (double)part1[j * LSEQ + l];
        }
        w0d[l] = s0;
        w1d[l] = s1;
        double bv = (double)bvec[l];
        r0[l] = bv;
        r1[l] = (double)(l - LSEQ) * bv;
    }
    __syncthreads();
    for (int l = tid; l < LSEQ; l += RTHREADS) {
        double g0 = 0.0, g1 = 0.0;
        for (int m = l - PAD; m <= l + PAD; ++m) {
            if (m >= 0 && m < LSEQ) { g0 += w0d[m]; g1 += w1d[m]; }
        }
        if (l == 0) {
            for (int m = 0; m < PAD; ++m) {
                double c = (double)(PAD - m);
                g0 += c * w0d[m]; g1 += c * w1d[m];
            }
        }
        if (l == LSEQ - 1) {
            for (int m = LSEQ - PAD; m < LSEQ; ++m) {
                double c = (double)(m - (LSEQ - PAD - 1));
                g0 += c * w0d[m]; g1 += c * w1d[m];
            }
        }
        g0 *= (1.0 / (double)KAVG);
        g1 *= (1.0 / (double)KAVG);
        la[l]  = (float)(I00 * g0 + I01 * g1);
        lbb[l] = (float)(I01 * g0 + I11 * g1);
    }
    // bias reduction tree: first step (s=256) needs only 256 threads
    for (int s = LSEQ / 2; s > 0; s >>= 1) {
        __syncthreads();
        if (tid < s) { r0[tid] += r0[tid + s]; r1[tid] += r1[tid + s]; }
    }
    if (tid == 0) {
        cc0 = (float)(I00 * r0[0] + I01 * r1[0]);
        cc1 = (float)(I01 * r0[0] + I11 * r1[0]);
    }
    __syncthreads();

    // ---- streaming accumulation: 4 rows (321 f32x4) per iteration ----
    int band = blockIdx.x;
    int b    = blockIdx.y;
    int l0   = band * BROWS;
    bool act = (tid < NCH);

    int e0 = 4 * tid;
    int q0 = e0 / NCH,       n0 = e0 - q0 * NCH;
    int q1 = (e0 + 1) / NCH, n1 = (e0 + 1) - q1 * NCH;
    int q2 = (e0 + 2) / NCH, n2 = (e0 + 2) - q2 * NCH;
    int q3 = (e0 + 3) / NCH, n3 = (e0 + 3) - q3 * NCH;

    float a0 = 0.f, a1 = 0.f, a2 = 0.f, a3 = 0.f;
    float c0 = 0.f, c1 = 0.f, c2 = 0.f, c3 = 0.f;
    if (act) {
        const f32x4* xp = reinterpret_cast<const f32x4*>(
            x + (size_t)b * (LSEQ * NCH) + (size_t)l0 * NCH);
#pragma unroll 8
        for (int g = 0; g < ITERS_V; ++g) {
            f32x4 v = xp[g * NCH + tid];
            int lb = l0 + 4 * g;
            a0 = fmaf(v.x, la[lb + q0], a0);  c0 = fmaf(v.x, lbb[lb + q0], c0);
            a1 = fmaf(v.y, la[lb + q1], a1);  c1 = fmaf(v.y, lbb[lb + q1], c1);
            a2 = fmaf(v.z, la[lb + q2], a2);  c2 = fmaf(v.z, lbb[lb + q2], c2);
            a3 = fmaf(v.w, la[lb + q3], a3);  c3 = fmaf(v.w, lbb[lb + q3], c3);
        }
    }

    // 4 race-free combine passes: t -> (4t+j) mod 321 is a permutation
    if (act) { cbuf0[n0] = a0;  cbuf1[n0] = c0; }
    __syncthreads();
    if (act) { cbuf0[n1] += a1; cbuf1[n1] += c1; }
    __syncthreads();
    if (act) { cbuf0[n2] += a2; cbuf1[n2] += c2; }
    __syncthreads();
    if (act) { cbuf0[n3] += a3; cbuf1[n3] += c3; }
    __syncthreads();

    if (tid < NCH) {
        float add0 = (band == 0) ? cc0 : 0.f;
        float add1 = (band == 0) ? cc1 : 0.f;
        P0[(band * BATCH + b) * NCH + tid] = cbuf0[tid] + add0;
        P1[(band * BATCH + b) * NCH + tid] = cbuf1[tid] + add1;
    }
}

// Stage 3 (write): out[b,p,n] = T0[b,n] + p*T1[b,n], T = sum of band partials.
// Each block writes 32 full rows (41 KB contiguous) of one batch, nt f32x4.
__global__ __launch_bounds__(256) void write_kernel(const float* __restrict__ P0,
                                                    const float* __restrict__ P1,
                                                    float* __restrict__ out) {
    __shared__ float t0s[NCH], t1s[NCH];
    int tid = threadIdx.x;
    int b = blockIdx.y;
    for (int i = tid; i < NCH; i += 256) {
        float s0 = 0.f, s1 = 0.f;
#pragma unroll
        for (int band = 0; band < BANDS; ++band) {
            s0 += P0[(band * BATCH + b) * NCH + i];
            s1 += P1[(band * BATCH + b) * NCH + i];
        }
        t0s[i] = s0;
        t1s[i] = s1;
    }
    __syncthreads();

    int pbase = blockIdx.x * ROWS_W;
    float* op = out + (size_t)b * (LSEQ * NCH) + (size_t)pbase * NCH;
    for (int g = tid; g < CHUNKW / 4; g += 256) {
        int c0 = 4 * g;
        int ploc = c0 / NCH;
        int n = c0 - ploc * NCH;
        float pf = (float)(pbase + ploc);
        f32x4 v;
        v.x = fmaf(pf, t1s[n], t0s[n]); if (++n == NCH) { n = 0; pf += 1.f; }
        v.y = fmaf(pf, t1s[n], t0s[n]); if (++n == NCH) { n = 0; pf += 1.f; }
        v.z = fmaf(pf, t1s[n], t0s[n]); if (++n == NCH) { n = 0; pf += 1.f; }
        v.w = fmaf(pf, t1s[n], t0s[n]);
        __builtin_nontemporal_store(v, reinterpret_cast<f32x4*>(op + c0));
    }
}

extern "C" void kernel_launch(void* const* d_in, const int* in_sizes, int n_in,
                              void* d_out, int out_size, void* d_ws, size_t ws_size,
                              hipStream_t stream) {
    (void)in_sizes; (void)n_in; (void)out_size; (void)ws_size;
    const float* x    = (const float*)d_in[0];
    const float* W    = (const float*)d_in[1];
    const float* bvec = (const float*)d_in[2];
    float* out = (float*)d_out;

    // ws layout: [part0 8*512][part1 8*512][P0 8*128*321][P1 8*128*321]
    float* p0 = (float*)d_ws;
    float* p1 = p0 + NB1A * LSEQ;
    float* P0 = p1 + NB1A * LSEQ;
    float* P1 = P0 + BANDS * BATCH * NCH;

    colsum_kernel<<<NB1A, LSEQ, 0, stream>>>(W, p0, p1);
    reduce_kernel<<<dim3(BANDS, BATCH), RTHREADS, 0, stream>>>(x, p0, p1, bvec, P0, P1);
    write_kernel<<<dim3(WBLOCKS, BATCH), 256, 0, stream>>>(P0, P1, out);
}

// Round 10
// 42.468 us; speedup vs baseline: 1.3379x; 1.3379x over previous
//
#include <hip/hip_runtime.h>

#define LSEQ 512
#define NCH  321
#define BATCH 128
#define KAVG 25
#define PAD  12
#define NB1A 8
#define ROWS1A 64      // LSEQ / NB1A

#define BANDS 4
#define BROWS 128      // rows per band (LSEQ / BANDS)
#define ITERS 64       // BROWS / 2 (two rows per iteration)
#define RTHREADS 704   // 11 waves; 2*NCH = 642 active lanes

#define ROWS_W 32
#define WBLOCKS (LSEQ / ROWS_W)   // 16
#define CHUNKW  (ROWS_W * NCH)    // 10272 dwords, /4 = 2568 float4

typedef float f32x4 __attribute__((ext_vector_type(4)));

// Exact XTX for t = -512..-1:  [[L, S1],[S1, S2]]
constexpr double S1d  = -131328.0;
constexpr double S2d  = 44870400.0;
constexpr double DETD = 512.0 * S2d - S1d * S1d;
constexpr double I00  = S2d / DETD;
constexpr double I01  = -S1d / DETD;
constexpr double I11  = 512.0 / DETD;

// Stage 1: partial column sums of W (row-major [p][l]), 64 rows per block.
__global__ __launch_bounds__(512) void colsum_kernel(const float* __restrict__ W,
                                                     float* __restrict__ part0,
                                                     float* __restrict__ part1) {
    int l = threadIdx.x;
    int p0 = blockIdx.x * ROWS1A;
    double s0 = 0.0, s1 = 0.0;
#pragma unroll
    for (int r = 0; r < ROWS1A; ++r) {
        float w = W[(p0 + r) * LSEQ + l];
        s0 += (double)w;
        s1 += (double)(p0 + r - LSEQ) * (double)w;
    }
    part0[blockIdx.x * LSEQ + l] = (float)s0;
    part1[blockIdx.x * LSEQ + l] = (float)s1;
}

// Stage 2 (reduce, streaming): block = (band, b). Inline prep prologue builds
// alpha/beta (+ bias consts) in LDS, then the block streams 128 contiguous
// rows of x (two rows per iteration across 642 lanes), each thread owning a
// fixed channel n. Band partials go to P0/P1; consts folded into band 0.
__global__ __launch_bounds__(RTHREADS) void reduce_kernel(const float* __restrict__ x,
                                                          const float* __restrict__ part0,
                                                          const float* __restrict__ part1,
                                                          const float* __restrict__ bvec,
                                                          float* __restrict__ P0,
                                                          float* __restrict__ P1) {
    __shared__ double w0d[LSEQ], w1d[LSEQ];
    __shared__ double r0[LSEQ], r1[LSEQ];
    __shared__ float la[LSEQ], lbb[LSEQ];
    __shared__ float cbuf0[NCH], cbuf1[NCH];
    __shared__ float cc0, cc1;

    int tid = threadIdx.x;

    // ---- inline prep (threads 0..511) ----
    if (tid < LSEQ) {
        int l = tid;
        double s0 = 0.0, s1 = 0.0;
#pragma unroll
        for (int j = 0; j < NB1A; ++j) {
            s0 += (double)part0[j * LSEQ + l];
            s1 += (double)part1[j * LSEQ + l];
        }
        w0d[l] = s0;
        w1d[l] = s1;
        double bv = (double)bvec[l];
        r0[l] = bv;
        r1[l] = (double)(l - LSEQ) * bv;
    }
    __syncthreads();
    if (tid < LSEQ) {
        int l = tid;
        double g0 = 0.0, g1 = 0.0;
        for (int m = l - PAD; m <= l + PAD; ++m) {
            if (m >= 0 && m < LSEQ) { g0 += w0d[m]; g1 += w1d[m]; }
        }
        if (l == 0) {
            for (int m = 0; m < PAD; ++m) {
                double c = (double)(PAD - m);
                g0 += c * w0d[m]; g1 += c * w1d[m];
            }
        }
        if (l == LSEQ - 1) {
            for (int m = LSEQ - PAD; m < LSEQ; ++m) {
                double c = (double)(m - (LSEQ - PAD - 1));
                g0 += c * w0d[m]; g1 += c * w1d[m];
            }
        }
        g0 *= (1.0 / (double)KAVG);
        g1 *= (1.0 / (double)KAVG);
        la[l]  = (float)(I00 * g0 + I01 * g1);
        lbb[l] = (float)(I01 * g0 + I11 * g1);
    }
    for (int s = LSEQ / 2; s > 0; s >>= 1) {
        __syncthreads();
        if (tid < s) { r0[tid] += r0[tid + s]; r1[tid] += r1[tid + s]; }
    }
    if (tid == 0) {
        cc0 = (float)(I00 * r0[0] + I01 * r1[0]);
        cc1 = (float)(I01 * r0[0] + I11 * r1[0]);
    }
    __syncthreads();

    // ---- streaming accumulation: two full rows per iteration ----
    int band = blockIdx.x;
    int b    = blockIdx.y;
    int half = (tid >= NCH) ? 1 : 0;
    int n    = tid - half * NCH;
    bool act = (tid < 2 * NCH);
    int l0   = band * BROWS;

    float a = 0.f, bb = 0.f;
    if (act) {
        const float* xp = x + (size_t)b * (LSEQ * NCH) + (size_t)l0 * NCH + tid;
#pragma unroll 8
        for (int it = 0; it < ITERS; ++it) {
            float v = xp[it * (2 * NCH)];
            int l = l0 + 2 * it + half;
            a  = fmaf(v, la[l],  a);
            bb = fmaf(v, lbb[l], bb);
        }
    }

    // combine the two half-row owners of each n (deterministic two-step)
    if (act && half == 0) { cbuf0[n] = a; cbuf1[n] = bb; }
    __syncthreads();
    if (act && half == 1) { cbuf0[n] += a; cbuf1[n] += bb; }
    __syncthreads();

    if (tid < NCH) {
        float add0 = (band == 0) ? cc0 : 0.f;
        float add1 = (band == 0) ? cc1 : 0.f;
        P0[(band * BATCH + b) * NCH + tid] = cbuf0[tid] + add0;
        P1[(band * BATCH + b) * NCH + tid] = cbuf1[tid] + add1;
    }
}

// Stage 3 (write): out[b,p,n] = T0[b,n] + p*T1[b,n], T = sum of band partials.
// Each block writes 32 full rows (41 KB contiguous) of one batch.
// Nontemporal stores: out is write-once, never read — keep it out of L2/L3
// so x stays LLC-resident across timed replays.
__global__ __launch_bounds__(256) void write_kernel(const float* __restrict__ P0,
                                                    const float* __restrict__ P1,
                                                    float* __restrict__ out) {
    __shared__ float t0s[NCH], t1s[NCH];
    int tid = threadIdx.x;
    int b = blockIdx.y;
    for (int i = tid; i < NCH; i += 256) {
        float s0 = 0.f, s1 = 0.f;
#pragma unroll
        for (int band = 0; band < BANDS; ++band) {
            s0 += P0[(band * BATCH + b) * NCH + i];
            s1 += P1[(band * BATCH + b) * NCH + i];
        }
        t0s[i] = s0;
        t1s[i] = s1;
    }
    __syncthreads();

    int pbase = blockIdx.x * ROWS_W;
    float* op = out + (size_t)b * (LSEQ * NCH) + (size_t)pbase * NCH;
    for (int g = tid; g < CHUNKW / 4; g += 256) {
        int c0 = 4 * g;
        int ploc = c0 / NCH;
        int n = c0 - ploc * NCH;
        float pf = (float)(pbase + ploc);
        f32x4 v;
        v.x = fmaf(pf, t1s[n], t0s[n]); if (++n == NCH) { n = 0; pf += 1.f; }
        v.y = fmaf(pf, t1s[n], t0s[n]); if (++n == NCH) { n = 0; pf += 1.f; }
        v.z = fmaf(pf, t1s[n], t0s[n]); if (++n == NCH) { n = 0; pf += 1.f; }
        v.w = fmaf(pf, t1s[n], t0s[n]);
        __builtin_nontemporal_store(v, reinterpret_cast<f32x4*>(op + c0));
    }
}

extern "C" void kernel_launch(void* const* d_in, const int* in_sizes, int n_in,
                              void* d_out, int out_size, void* d_ws, size_t ws_size,
                              hipStream_t stream) {
    (void)in_sizes; (void)n_in; (void)out_size; (void)ws_size;
    const float* x    = (const float*)d_in[0];
    const float* W    = (const float*)d_in[1];
    const float* bvec = (const float*)d_in[2];
    float* out = (float*)d_out;

    // ws layout: [part0 8*512][part1 8*512][P0 4*128*321][P1 4*128*321]
    float* p0 = (float*)d_ws;
    float* p1 = p0 + NB1A * LSEQ;
    float* P0 = p1 + NB1A * LSEQ;
    float* P1 = P0 + BANDS * BATCH * NCH;

    colsum_kernel<<<NB1A, LSEQ, 0, stream>>>(W, p0, p1);
    reduce_kernel<<<dim3(BANDS, BATCH), RTHREADS, 0, stream>>>(x, p0, p1, bvec, P0, P1);
    write_kernel<<<dim3(WBLOCKS, BATCH), 256, 0, stream>>>(P0, P1, out);
}